// Round 1
// baseline (265.694 us; speedup 1.0000x reference)
//
#include <hip/hip_runtime.h>
#include <stdint.h>

#define B_ 32
#define F_ 8
#define H_ 224
#define W_ 224
#define NPIX (H_ * W_)          // 50176
#define NFRAMES (B_ * F_)       // 256
#define CHSTRIDE (F_ * H_ * W_) // 401408 (elements between channels)

// ---------------- Kernel 1: gray quantization ----------------
__device__ __forceinline__ uint8_t quant1(float s) {
    float gr = s / 3.0f;                 // mean over 3 channels
    float v = floorf(gr * 255.0f);
    v = fminf(fmaxf(v, 0.0f), 255.0f);
    return (uint8_t)(int)v;
}

__global__ __launch_bounds__(256) void k_gray(const float* __restrict__ x,
                                              uchar4* __restrict__ g4, int nq4) {
    int t = blockIdx.x * blockDim.x + threadIdx.x;
    if (t >= nq4) return;
    int q = t * 4;                        // pixel index over (B,F,H,W), < 12.8M
    int b = q / CHSTRIDE;
    int rem = q - b * CHSTRIDE;
    const float4* p0 = reinterpret_cast<const float4*>(x + (size_t)(b * 3 + 0) * CHSTRIDE + rem);
    const float4* p1 = reinterpret_cast<const float4*>(x + (size_t)(b * 3 + 1) * CHSTRIDE + rem);
    const float4* p2 = reinterpret_cast<const float4*>(x + (size_t)(b * 3 + 2) * CHSTRIDE + rem);
    float4 a = *p0, bb = *p1, c = *p2;
    uchar4 o;
    o.x = quant1(a.x + bb.x + c.x);
    o.y = quant1(a.y + bb.y + c.y);
    o.z = quant1(a.z + bb.z + c.z);
    o.w = quant1(a.w + bb.w + c.w);
    g4[t] = o;
}

// ---------------- block reduction (double, 16 waves of 64) ----------------
__device__ __forceinline__ double blockReduceD(double v, double* red) {
    #pragma unroll
    for (int off = 32; off; off >>= 1) v += __shfl_down(v, off, 64);
    int lane = threadIdx.x & 63;
    int wave = threadIdx.x >> 6;
    __syncthreads();                 // protect red[] from previous use
    if (lane == 0) red[wave] = v;
    __syncthreads();
    double t = 0.0;
    #pragma unroll
    for (int w = 0; w < 16; ++w) t += red[w];
    return t;                        // broadcast to all threads
}

// ---------------- Kernel 2: GLCM features, one frame per block ----------------
__global__ __launch_bounds__(1024) void k_glcm(const uint8_t* __restrict__ g,
                                               float* __restrict__ out) {
    __shared__ uint32_t hist[32768];   // 128 KB: 256x256 u16 counts, packed 2/word
    __shared__ double red[16];

    const int frame = blockIdx.x;
    const uint8_t* __restrict__ gf = g + (size_t)frame * NPIX;
    const int tid  = threadIdx.x;
    const int lane = tid & 63;
    const int wave = tid >> 6;

    // ---- std over the frame (exact integer sums) ----
    uint32_t s1 = 0, s2 = 0;
    for (int i = tid; i < NPIX; i += 1024) {
        int v = gf[i];
        s1 += (uint32_t)v;
        s2 += (uint32_t)(v * v);
    }
    double sum1 = blockReduceD((double)s1, red);
    double sum2 = blockReduceD((double)s2, red);

    double conA = 0.0, disA = 0.0, homA = 0.0, asmA = 0.0;

    const int drs[4] = {0, 1, 1, 1};
    const int dcs[4] = {1, 1, 0, -1};

    #pragma unroll
    for (int o = 0; o < 4; ++o) {
        const int dr = drs[o], dc = dcs[o];
        const int nr = H_ - dr;
        const int nc = W_ - (dc ? 1 : 0);
        const int c0 = (dc < 0) ? 1 : 0;
        const int np = nr * nc;

        // zero histogram
        for (int i = tid; i < 32768; i += 1024) hist[i] = 0u;
        __syncthreads();

        // pair loop: rows per wave, cols per lane (coalesced byte loads)
        uint32_t conI = 0, disI = 0;
        float homF = 0.0f;
        for (int r = wave; r < nr; r += 16) {
            const uint8_t* rowA = gf + r * W_ + c0;
            const uint8_t* rowB = gf + (r + dr) * W_ + c0 + dc;
            for (int c = lane; c < nc; c += 64) {
                int a = rowA[c];
                int b = rowB[c];
                int idx = (a << 8) | b;
                atomicAdd(&hist[idx >> 1], 1u << ((idx & 1) << 4));
                int d = a - b;
                int d2 = d * d;
                conI += (uint32_t)d2;
                disI += (uint32_t)(d < 0 ? -d : d);
                homF += 1.0f / (1.0f + (float)d2);
            }
        }
        __syncthreads();

        // ASM pass: S = sum over all (i,j) of (h[i][j] + h[j][i])^2
        // Diagonal assignment: lane -> i, wave -> d = (j - i) mod 256.
        // Both reads stride 257 elements across lanes => <=2-way bank alias (free).
        unsigned long long S = 0ull;
        for (int dd = wave; dd < 256; dd += 16) {
            for (int ib = 0; ib < 256; ib += 64) {
                int i = ib + lane;
                int j = (i + dd) & 255;
                int idx = (i << 8) | j;
                int jdx = (j << 8) | i;
                uint32_t hij = (hist[idx >> 1] >> ((idx & 1) << 4)) & 0xffffu;
                uint32_t hji = (hist[jdx >> 1] >> ((jdx & 1) << 4)) & 0xffffu;
                uint32_t v = hij + hji;
                S += (unsigned long long)v * (unsigned long long)v;
            }
        }

        double conS = blockReduceD((double)conI, red);   // syncthreads inside
        double disS = blockReduceD((double)disI, red);
        double homS = blockReduceD((double)homF, red);
        double Ssum = blockReduceD((double)S, red);

        double inv = 1.0 / (double)np;
        conA += conS * inv;
        disA += disS * inv;
        homA += homS * inv;
        asmA += Ssum / (4.0 * (double)np * (double)np);
    }

    if (tid == 0) {
        double N = (double)NPIX;
        double mean = sum1 / N;
        double var = sum2 / N - mean * mean;
        if (var < 0.0) var = 0.0;
        double sd = sqrt(var);
        double conv = conA * 0.25;
        double disv = disA * 0.25;
        double homv = homA * 0.25;
        double asmv = asmA * 0.25;
        float* op = out + frame * 6;
        op[0] = (float)sd;
        op[1] = (float)conv;
        op[2] = (float)disv;
        op[3] = (float)homv;
        op[4] = (float)asmv;
        op[5] = (float)sqrt(asmv);
    }
}

extern "C" void kernel_launch(void* const* d_in, const int* in_sizes, int n_in,
                              void* d_out, int out_size, void* d_ws, size_t ws_size,
                              hipStream_t stream) {
    const float* x = (const float*)d_in[0];
    float* out = (float*)d_out;
    uint8_t* g = (uint8_t*)d_ws;         // 12,845,056 bytes needed

    const int npix_total = B_ * F_ * H_ * W_;   // 12,845,056
    const int nq4 = npix_total / 4;             // 3,211,264
    const int blocks1 = (nq4 + 255) / 256;      // 12,544

    k_gray<<<blocks1, 256, 0, stream>>>(x, (uchar4*)g, nq4);
    k_glcm<<<NFRAMES, 1024, 0, stream>>>(g, out);
}